// Round 12
// baseline (788.868 us; speedup 1.0000x reference)
//
#include <hip/hip_runtime.h>

#define NNODES 50000
#define NEDGES 400000
#define NMOLS  2000
#define NBLK   196   // ceil(NNODES/256)

// ---- ws layout (4-byte units), total 5,350,256 * 4B = 21.4 MB ----
constexpr size_t OFF_CNT   = 0;         // 50000 int (zeroed each call)
constexpr size_t OFF_OFFS  = 50000;     // 50000 int
constexpr size_t OFF_CURS  = 100000;    // 50000 int
constexpr size_t OFF_BSUM  = 150000;    // 256 int
constexpr size_t OFF_SRCS  = 150256;    // 400000 int (CSR-ordered src)
constexpr size_t OFF_EB4   = 550256;    // 400000*4 floats (dx,dy,dz,w0), 16B rows
constexpr size_t OFF_GB    = 2150256;   // 50000*16 uints (26 bf16 + pad = 64B rows)
constexpr size_t OFF_AB    = 2950256;   // 50000*32 uints (54 bf16 + pad = 128B rows)
constexpr size_t OFF_HH    = 4550256;   // 50000*16 floats (9 used, 64B rows)
// end: 5,350,256

__device__ __forceinline__ unsigned short f2bf(float f) {
  unsigned int b = __float_as_uint(f);
  unsigned int r = (b + 0x7FFFu + ((b >> 16) & 1u)) >> 16;  // RNE
  return (unsigned short)r;
}
__device__ __forceinline__ float bflo(unsigned int u) { return __uint_as_float(u << 16); }
__device__ __forceinline__ float bfhi(unsigned int u) { return __uint_as_float(u & 0xFFFF0000u); }
__device__ __forceinline__ unsigned int packbf(float a, float b) {
  return (unsigned int)f2bf(a) | ((unsigned int)f2bf(b) << 16);
}

__device__ __forceinline__ void make_b(float w0, float dx, float dy, float dz, float* b) {
  const float s3 = 1.7320508075688772f, s5c = 2.2360679774997896f, s15 = 3.872983346207417f;
  float r2 = dx * dx + dy * dy + dz * dz;
  b[0] = w0;
  b[1] = w0 * s3 * dy;
  b[2] = w0 * s3 * dz;
  b[3] = w0 * s3 * dx;
  b[4] = w0 * s15 * dx * dy;
  b[5] = w0 * s15 * dy * dz;
  b[6] = w0 * 0.5f * s5c * (3.f * dz * dz - r2);
  b[7] = w0 * s15 * dx * dz;
  b[8] = w0 * 0.5f * s15 * (dx * dx - dy * dy);
}

// ---------- CSR build ----------
__global__ void k_count(const int* __restrict__ dst, int* __restrict__ cnt) {
  int e = blockIdx.x * blockDim.x + threadIdx.x;
  if (e < NEDGES) atomicAdd(cnt + dst[e], 1);
}

__global__ void k_scanA(const int* __restrict__ cnt, int* __restrict__ offs, int* __restrict__ bsum) {
  __shared__ int sh[256];
  int t = threadIdx.x, i = blockIdx.x * 256 + t;
  int c = (i < NNODES) ? cnt[i] : 0;
  sh[t] = c; __syncthreads();
  #pragma unroll
  for (int off = 1; off < 256; off <<= 1) {
    int v = (t >= off) ? sh[t - off] : 0; __syncthreads();
    sh[t] += v; __syncthreads();
  }
  if (i < NNODES) offs[i] = sh[t] - c;
  if (t == 255) bsum[blockIdx.x] = sh[255];
}

__global__ void k_scanB(int* __restrict__ bsum) {
  __shared__ int sh[256];
  int t = threadIdx.x;
  int v = (t < NBLK) ? bsum[t] : 0;
  sh[t] = v; __syncthreads();
  #pragma unroll
  for (int off = 1; off < 256; off <<= 1) {
    int u = (t >= off) ? sh[t - off] : 0; __syncthreads();
    sh[t] += u; __syncthreads();
  }
  bsum[t] = sh[t] - v;
}

__global__ void k_scanC(int* __restrict__ offs, int* __restrict__ curs, const int* __restrict__ bsum) {
  int i = blockIdx.x * 256 + threadIdx.x;
  if (i < NNODES) {
    int o = offs[i] + bsum[blockIdx.x];
    offs[i] = o;
    curs[i] = o;
  }
}

__global__ void k_fill(const float* __restrict__ pos, const float* __restrict__ ea,
                       const int* __restrict__ src, const int* __restrict__ dst,
                       int* __restrict__ curs, int* __restrict__ srcs, float4* __restrict__ eb4) {
  int e = blockIdx.x * blockDim.x + threadIdx.x;
  if (e >= NEDGES) return;
  int s = src[e], d = dst[e];
  int p = atomicAdd(curs + d, 1);
  srcs[p] = s;
  float dx = pos[3 * s] - pos[3 * d];
  float dy = pos[3 * s + 1] - pos[3 * d + 1];
  float dz = pos[3 * s + 2] - pos[3 * d + 2];
  eb4[p] = make_float4(dx, dy, dz, ea[(size_t)e * 7]);
}

// ---------- node linear + TP1 precompute (bf16-packed g, one 64B line/row) ----------
__global__ void __launch_bounds__(256, 2)
k_node1(const float* __restrict__ x, const float* __restrict__ lw,
        const float* __restrict__ lb, const float* __restrict__ w1,
        unsigned int* __restrict__ gb) {
  int n = blockIdx.x * blockDim.x + threadIdx.x;
  if (n >= NNODES) return;
  float f[23];
  const float* xr = x + (size_t)n * 23;
  #pragma unroll
  for (int v = 0; v < 23; ++v) {
    float acc = lb[v];
    const float* wr = lw + v * 23;
    #pragma unroll
    for (int c = 0; c < 23; ++c) acc += xr[c] * wr[c];
    f[v] = fmaxf(acc, 0.f);
  }
  float G[26];
  #pragma unroll
  for (int w = 0; w < 16; ++w) { float a = 0; for (int v = 0; v < 23; ++v) a += f[v] * w1[v * 16 + w]; G[w] = a; }
  #pragma unroll
  for (int w = 0; w < 6;  ++w) { float a = 0; for (int v = 0; v < 23; ++v) a += f[v] * w1[368 + v * 6 + w]; G[16 + w] = a; }
  #pragma unroll
  for (int w = 0; w < 4;  ++w) { float a = 0; for (int v = 0; v < 23; ++v) a += f[v] * w1[506 + v * 4 + w]; G[22 + w] = a; }
  unsigned int U[16];
  #pragma unroll
  for (int i = 0; i < 13; ++i) U[i] = packbf(G[2 * i], G[2 * i + 1]);
  U[13] = U[14] = U[15] = 0u;
  uint4* o = (uint4*)(gb + (size_t)n * 16);
  o[0] = make_uint4(U[0], U[1], U[2], U[3]);
  o[1] = make_uint4(U[4], U[5], U[6], U[7]);
  o[2] = make_uint4(U[8], U[9], U[10], U[11]);
  o[3] = make_uint4(U[12], U[13], U[14], U[15]);
}

// ---------- layer 1 gather: 8 lanes per node; writes bf16 A-row (128B) ----------
__global__ void __launch_bounds__(256, 2)
k_gather1(const int* __restrict__ offs, const int* __restrict__ cnt,
          const int* __restrict__ srcs, const float4* __restrict__ eb4,
          const unsigned int* __restrict__ gb, unsigned int* __restrict__ ab) {
  int tid = blockIdx.x * 256 + threadIdx.x;
  int n = tid >> 3, sl = tid & 7;
  if (n >= NNODES) return;
  int beg = offs[n], cn = cnt[n];
  float M[54];
  #pragma unroll
  for (int i = 0; i < 54; ++i) M[i] = 0.f;
  for (int j = sl; j < cn; j += 8) {
    int p = beg + j;
    int s = srcs[p];
    float4 ebv = eb4[p];
    float bb[9]; make_b(ebv.w, ebv.x, ebv.y, ebv.z, bb);
    const uint4* Gf = (const uint4*)(gb + (size_t)s * 16);
    uint4 u0 = Gf[0], u1 = Gf[1], u2 = Gf[2], u3 = Gf[3];
    unsigned int U[13] = { u0.x, u0.y, u0.z, u0.w, u1.x, u1.y, u1.z, u1.w,
                           u2.x, u2.y, u2.z, u2.w, u3.x };
    #pragma unroll
    for (int u = 0; u < 16; ++u) {
      float gv = (u & 1) ? bfhi(U[u >> 1]) : bflo(U[u >> 1]);
      M[u] += bb[0] * gv;
    }
    #pragma unroll
    for (int u = 0; u < 6; ++u) {
      int idx = 16 + u;
      float gv = (idx & 1) ? bfhi(U[idx >> 1]) : bflo(U[idx >> 1]);
      #pragma unroll
      for (int k = 0; k < 3; ++k) M[16 + 3 * u + k] += bb[1 + k] * gv;
    }
    #pragma unroll
    for (int u = 0; u < 4; ++u) {
      int idx = 22 + u;
      float gv = (idx & 1) ? bfhi(U[idx >> 1]) : bflo(U[idx >> 1]);
      #pragma unroll
      for (int K = 0; K < 5; ++K) M[34 + 5 * u + K] += bb[4 + K] * gv;
    }
  }
  #pragma unroll
  for (int m = 1; m < 8; m <<= 1)
    #pragma unroll
    for (int i = 0; i < 54; ++i) M[i] += __shfl_xor(M[i], m);
  if (sl == 0) {
    const float S23 = 0.20851441405707477f;
    float sc = S23 * rsqrtf((float)cn);
    unsigned int U[32];
    #pragma unroll
    for (int i = 0; i < 27; ++i) U[i] = packbf(sc * M[2 * i], sc * M[2 * i + 1]);
    #pragma unroll
    for (int i = 27; i < 32; ++i) U[i] = 0u;
    uint4* o4 = (uint4*)(ab + (size_t)n * 32);
    #pragma unroll
    for (int q = 0; q < 8; ++q)
      o4[q] = make_uint4(U[4 * q], U[4 * q + 1], U[4 * q + 2], U[4 * q + 3]);
  }
}

// ---------- layer 2 FUSED: on-edge TP2 from bf16 A-row (6.4MB, near-L2-resident), 256-VGPR cap ----------
__global__ void __launch_bounds__(256, 1)
k_edge2c(const int* __restrict__ offs, const int* __restrict__ cnt,
         const int* __restrict__ srcs, const float4* __restrict__ eb4,
         const unsigned int* __restrict__ ab, const float* __restrict__ w2,
         const float* __restrict__ w3, float* __restrict__ hh) {
  __shared__ float W[596];
  for (int i = threadIdx.x; i < 596; i += 256) W[i] = w2[i];
  __syncthreads();
  int tid = blockIdx.x * 256 + threadIdx.x;
  int n = tid >> 3, sl = tid & 7;
  if (n >= NNODES) return;
  int beg = offs[n], cn = cnt[n];
  float O0[8], O2[9], O3[10];
  #pragma unroll
  for (int i = 0; i < 8; ++i) O0[i] = 0.f;
  #pragma unroll
  for (int i = 0; i < 9; ++i) O2[i] = 0.f;
  #pragma unroll
  for (int i = 0; i < 10; ++i) O3[i] = 0.f;

  const float I3 = 0.5773502691896258f, I5 = 0.4472135954999579f;
  const float CA = 0.18257418583505536f, CB = 0.31622776601683794f, CC = 0.3651483716701107f;
  const float P = 0.2390457218668787f, Q = 0.2070196678027063f, R = 0.1195228609334394f;

  for (int j = sl; j < cn; j += 8) {
    int p = beg + j;
    int s = srcs[p];
    const uint4* Af = (const uint4*)(ab + (size_t)s * 32);
    uint4 Qv0 = Af[0], Qv1 = Af[1], Qv2 = Af[2], Qv3 = Af[3], Qv4 = Af[4], Qv5 = Af[5], Qv6 = Af[6];
    float4 ebv = eb4[p];
    float b[9]; make_b(ebv.w, ebv.x, ebv.y, ebv.z, b);

    // ---- section A0: A[0..15] ----
    {
      float A0[16] = {
        bflo(Qv0.x), bfhi(Qv0.x), bflo(Qv0.y), bfhi(Qv0.y),
        bflo(Qv0.z), bfhi(Qv0.z), bflo(Qv0.w), bfhi(Qv0.w),
        bflo(Qv1.x), bfhi(Qv1.x), bflo(Qv1.y), bfhi(Qv1.y),
        bflo(Qv1.z), bfhi(Qv1.z), bflo(Qv1.w), bfhi(Qv1.w) };
      #pragma unroll
      for (int w = 0; w < 8; ++w) {
        float t0 = 0;
        #pragma unroll
        for (int u = 0; u < 16; ++u) t0 += A0[u] * W[u * 8 + w];
        O0[w] += b[0] * t0;
      }
      #pragma unroll
      for (int w = 0; w < 3; ++w) {
        float ta = 0;
        #pragma unroll
        for (int u = 0; u < 16; ++u) ta += A0[u] * W[128 + 3 * u + w];
        float c = I3 * ta;
        O2[3 * w + 0] += c * b[1];
        O2[3 * w + 1] += c * b[2];
        O2[3 * w + 2] += c * b[3];
      }
      #pragma unroll
      for (int w = 0; w < 2; ++w) {
        float ta = 0;
        #pragma unroll
        for (int u = 0; u < 16; ++u) ta += A0[u] * W[176 + 2 * u + w];
        float c = I5 * ta;
        #pragma unroll
        for (int K = 0; K < 5; ++K) O3[5 * w + K] += c * b[4 + K];
      }
    }

    // ---- section A1: A[16..33] ----
    {
      float A1[18] = {
        bflo(Qv2.x), bfhi(Qv2.x), bflo(Qv2.y), bfhi(Qv2.y),
        bflo(Qv2.z), bfhi(Qv2.z), bflo(Qv2.w), bfhi(Qv2.w),
        bflo(Qv3.x), bfhi(Qv3.x), bflo(Qv3.y), bfhi(Qv3.y),
        bflo(Qv3.z), bfhi(Qv3.z), bflo(Qv3.w), bfhi(Qv3.w),
        bflo(Qv4.x), bfhi(Qv4.x) };
      float CBb1_0 = CB * b[1], CBb1_1 = CB * b[2], CBb1_2 = CB * b[3];
      float CAb1_0 = CA * b[1], CAb1_2 = CA * b[3], CCb1_1 = CC * b[2];
      float c121_00 = -CA * b[6] - CB * b[8], c121_01 = CB * b[5], c121_02 = CB * b[4];
      float c121_11 = CC * b[6], c121_12 = CB * b[7], c121_22 = -CA * b[6] + CB * b[8];
      #pragma unroll
      for (int w = 0; w < 8; ++w) {
        float t1 = 0;
        #pragma unroll
        for (int jj = 0; jj < 3; ++jj) {
          float s1 = 0;
          #pragma unroll
          for (int u = 0; u < 6; ++u) s1 += A1[3 * u + jj] * W[316 + 8 * u + w];
          t1 += s1 * b[1 + jj];
        }
        O0[w] += I3 * t1;
      }
      #pragma unroll
      for (int w = 0; w < 3; ++w) {
        float tb[3], tc[3];
        #pragma unroll
        for (int k = 0; k < 3; ++k) {
          tb[k] = 0; tc[k] = 0;
          #pragma unroll
          for (int u = 0; u < 6; ++u) {
            tb[k] += A1[3 * u + k] * W[298 + 3 * u + w];
            tc[k] += A1[3 * u + k] * W[394 + 3 * u + w];
          }
        }
        O2[3 * w + 0] += I3 * b[0] * tb[0] + tc[0] * c121_00 + tc[1] * c121_01 + tc[2] * c121_02;
        O2[3 * w + 1] += I3 * b[0] * tb[1] + tc[0] * c121_01 + tc[1] * c121_11 + tc[2] * c121_12;
        O2[3 * w + 2] += I3 * b[0] * tb[2] + tc[0] * c121_02 + tc[1] * c121_12 + tc[2] * c121_22;
      }
      #pragma unroll
      for (int w = 0; w < 2; ++w) {
        float tc[3];
        #pragma unroll
        for (int i = 0; i < 3; ++i) {
          tc[i] = 0;
          #pragma unroll
          for (int u = 0; u < 6; ++u) tc[i] += A1[3 * u + i] * W[382 + 2 * u + w];
        }
        O3[5 * w + 0] += tc[0] * CBb1_2 + tc[2] * CBb1_0;
        O3[5 * w + 1] += tc[0] * CBb1_1 + tc[1] * CBb1_0;
        O3[5 * w + 2] += -tc[0] * CAb1_0 + tc[1] * CCb1_1 - tc[2] * CAb1_2;
        O3[5 * w + 3] += tc[1] * CBb1_2 + tc[2] * CBb1_1;
        O3[5 * w + 4] += -tc[0] * CBb1_0 + tc[2] * CBb1_2;
      }
    }

    // ---- section A2: A[34..53] ----
    {
      float A2[20] = {
        bflo(Qv4.y), bfhi(Qv4.y), bflo(Qv4.z), bfhi(Qv4.z), bflo(Qv4.w), bfhi(Qv4.w),
        bflo(Qv5.x), bfhi(Qv5.x), bflo(Qv5.y), bfhi(Qv5.y), bflo(Qv5.z), bfhi(Qv5.z),
        bflo(Qv5.w), bfhi(Qv5.w), bflo(Qv6.x), bfhi(Qv6.x), bflo(Qv6.y), bfhi(Qv6.y),
        bflo(Qv6.z), bfhi(Qv6.z) };
      float CBb1_0 = CB * b[1], CBb1_1 = CB * b[2], CBb1_2 = CB * b[3];
      float CAb1_0 = CA * b[1], CAb1_2 = CA * b[3], CCb1_1 = CC * b[2];
      float Pb2_0 = P * b[4], Pb2_2 = P * b[6], Pb2_4 = P * b[8];
      float Qb2_0 = Q * b[4], Qb2_1 = Q * b[5], Qb2_3 = Q * b[7], Qb2_4 = Q * b[8];
      float Rb2_1 = R * b[5], Rb2_2 = R * b[6], Rb2_3 = R * b[7];
      #pragma unroll
      for (int w = 0; w < 8; ++w) {
        float t2 = 0;
        #pragma unroll
        for (int J = 0; J < 5; ++J) {
          float s2 = 0;
          #pragma unroll
          for (int u = 0; u < 4; ++u) s2 += A2[5 * u + J] * W[472 + 8 * u + w];
          t2 += s2 * b[4 + J];
        }
        O0[w] += I5 * t2;
      }
      #pragma unroll
      for (int w = 0; w < 3; ++w) {
        float td[5];
        #pragma unroll
        for (int I = 0; I < 5; ++I) {
          td[I] = 0;
          #pragma unroll
          for (int u = 0; u < 4; ++u) td[I] += A2[5 * u + I] * W[444 + 3 * u + w];
        }
        O2[3 * w + 0] += td[0] * CBb1_2 + td[1] * CBb1_1 - td[2] * CAb1_0 - td[4] * CBb1_0;
        O2[3 * w + 1] += td[1] * CBb1_0 + td[2] * CCb1_1 + td[3] * CBb1_2;
        O2[3 * w + 2] += td[0] * CBb1_0 - td[2] * CAb1_2 + td[3] * CBb1_1 + td[4] * CBb1_2;
      }
      #pragma unroll
      for (int w = 0; w < 2; ++w) {
        float tb[5], td[5];
        #pragma unroll
        for (int K = 0; K < 5; ++K) {
          tb[K] = 0; td[K] = 0;
          #pragma unroll
          for (int u = 0; u < 4; ++u) {
            tb[K] += A2[5 * u + K] * W[436 + 2 * u + w];
            td[K] += A2[5 * u + K] * W[516 + 2 * u + w];
          }
        }
        O3[5 * w + 0] += I5 * b[0] * tb[0]
                       - Pb2_2 * td[0] + Qb2_3 * td[1] - Pb2_0 * td[2] + Qb2_1 * td[3];
        O3[5 * w + 1] += I5 * b[0] * tb[1]
                       + Qb2_3 * td[0] + (Rb2_2 - Qb2_4) * td[1] + Rb2_1 * td[2] + Qb2_0 * td[3] - Qb2_1 * td[4];
        O3[5 * w + 2] += I5 * b[0] * tb[2]
                       - Pb2_0 * td[0] + Rb2_1 * td[1] + Pb2_2 * td[2] + Rb2_3 * td[3] - Pb2_4 * td[4];
        O3[5 * w + 3] += I5 * b[0] * tb[3]
                       + Qb2_1 * td[0] + Qb2_0 * td[1] + Rb2_3 * td[2] + (Rb2_2 + Qb2_4) * td[3] + Qb2_3 * td[4];
        O3[5 * w + 4] += I5 * b[0] * tb[4]
                       - Qb2_1 * td[1] - Pb2_4 * td[2] + Qb2_3 * td[3] - Pb2_2 * td[4];
      }
    }
  }

  #pragma unroll
  for (int m = 1; m < 8; m <<= 1) {
    #pragma unroll
    for (int i = 0; i < 8; ++i) O0[i] += __shfl_xor(O0[i], m);
    #pragma unroll
    for (int i = 0; i < 9; ++i) O2[i] += __shfl_xor(O2[i], m);
    #pragma unroll
    for (int i = 0; i < 10; ++i) O3[i] += __shfl_xor(O3[i], m);
  }

  if (sl == 0) {
    const float S26 = 0.19611613513818404f, S14 = 0.2672612419124244f, S8 = 0.35355339059327373f;
    const float S13 = 0.2773500981126146f;
    float di = rsqrtf((float)cn);
    float F[27];
    #pragma unroll
    for (int w = 0; w < 8; ++w) F[w] = S26 * di * O0[w];
    #pragma unroll
    for (int i = 0; i < 9; ++i) F[8 + i] = S14 * di * O2[i];
    #pragma unroll
    for (int i = 0; i < 10; ++i) F[17 + i] = S8 * di * O3[i];

    float h[9];
    float t0 = 0;
    #pragma unroll
    for (int u = 0; u < 8; ++u) t0 += F[u] * w3[u];
    h[0] = S13 * t0;
    #pragma unroll
    for (int jj = 0; jj < 3; ++jj) {
      float s1 = 0;
      #pragma unroll
      for (int u = 0; u < 3; ++u) s1 += F[8 + 3 * u + jj] * w3[8 + u];
      h[1 + jj] = S13 * I3 * s1;
    }
    #pragma unroll
    for (int K = 0; K < 5; ++K)
      h[4 + K] = S13 * I5 * (F[17 + K] * w3[11] + F[22 + K] * w3[12]);

    float4* o4 = (float4*)(hh + (size_t)n * 16);
    o4[0] = make_float4(h[0], h[1], h[2], h[3]);
    o4[1] = make_float4(h[4], h[5], h[6], h[7]);
    o4[2] = make_float4(h[8], 0.f, 0.f, 0.f);
  }
}

// ---------- layer 3 gather + molecule reduce ----------
__global__ void k_gather3(const int* __restrict__ offs, const int* __restrict__ cnt,
                          const int* __restrict__ srcs, const float4* __restrict__ eb4,
                          const float* __restrict__ hh, const int* __restrict__ batch,
                          float* __restrict__ out) {
  int tid = blockIdx.x * 256 + threadIdx.x;
  int n = tid >> 3, sl = tid & 7;
  if (n >= NNODES) return;
  int beg = offs[n], cn = cnt[n];
  float v = 0.f;
  for (int j = sl; j < cn; j += 8) {
    int p = beg + j;
    int s = srcs[p];
    float4 ebv = eb4[p];
    float b[9]; make_b(ebv.w, ebv.x, ebv.y, ebv.z, b);
    const float4* Hf = (const float4*)(hh + (size_t)s * 16);
    float4 hA = Hf[0], hB = Hf[1];
    float h8 = Hf[2].x;
    v += b[0] * hA.x + b[1] * hA.y + b[2] * hA.z + b[3] * hA.w
       + b[4] * hB.x + b[5] * hB.y + b[6] * hB.z + b[7] * hB.w
       + b[8] * h8;
  }
  #pragma unroll
  for (int m = 1; m < 8; m <<= 1) v += __shfl_xor(v, m);
  if (sl == 0) {
    float di = rsqrtf((float)cn);
    unsafeAtomicAdd(out + batch[n], v * di * 0.2f);  // /sqrt(apm)=/5
  }
}

extern "C" void kernel_launch(void* const* d_in, const int* in_sizes, int n_in,
                              void* d_out, int out_size, void* d_ws, size_t ws_size,
                              hipStream_t stream) {
  const float* positions = (const float*)d_in[0];
  const float* x         = (const float*)d_in[1];
  const float* edge_attr = (const float*)d_in[2];
  const float* lin_w     = (const float*)d_in[3];
  const float* lin_b     = (const float*)d_in[4];
  const float* w_tp1     = (const float*)d_in[5];
  const float* w_tp2     = (const float*)d_in[6];
  const float* w_tp3     = (const float*)d_in[7];
  const int*   edge_src  = (const int*)d_in[8];
  const int*   edge_dst  = (const int*)d_in[9];
  const int*   batch     = (const int*)d_in[10];
  float* out = (float*)d_out;

  int*   cnt  = (int*)d_ws + OFF_CNT;
  int*   offs = (int*)d_ws + OFF_OFFS;
  int*   curs = (int*)d_ws + OFF_CURS;
  int*   bsum = (int*)d_ws + OFF_BSUM;
  int*   srcs = (int*)d_ws + OFF_SRCS;
  float4* eb4 = (float4*)((float*)d_ws + OFF_EB4);
  unsigned int* gb = (unsigned int*)((float*)d_ws + OFF_GB);
  unsigned int* ab = (unsigned int*)((float*)d_ws + OFF_AB);
  float* hh   = (float*)d_ws + OFF_HH;

  hipMemsetAsync(cnt, 0, NNODES * sizeof(int), stream);
  hipMemsetAsync(out, 0, (size_t)out_size * sizeof(float), stream);

  dim3 blk256(256);
  dim3 gEdge((NEDGES + 255) / 256);
  dim3 gNode256((NNODES + 255) / 256);
  dim3 gCoop((NNODES * 8 + 255) / 256);

  k_count<<<gEdge, blk256, 0, stream>>>(edge_dst, cnt);
  k_scanA<<<dim3(NBLK), blk256, 0, stream>>>(cnt, offs, bsum);
  k_scanB<<<dim3(1), blk256, 0, stream>>>(bsum);
  k_scanC<<<dim3(NBLK), blk256, 0, stream>>>(offs, curs, bsum);
  k_fill<<<gEdge, blk256, 0, stream>>>(positions, edge_attr, edge_src, edge_dst, curs, srcs, eb4);
  k_node1<<<gNode256, blk256, 0, stream>>>(x, lin_w, lin_b, w_tp1, gb);
  k_gather1<<<gCoop, blk256, 0, stream>>>(offs, cnt, srcs, eb4, gb, ab);
  k_edge2c<<<gCoop, blk256, 0, stream>>>(offs, cnt, srcs, eb4, ab, w_tp2, w_tp3, hh);
  k_gather3<<<gCoop, blk256, 0, stream>>>(offs, cnt, srcs, eb4, hh, batch, out);
}

// Round 13
// 164.463 us; speedup vs baseline: 4.7966x; 4.7966x over previous
//
#include <hip/hip_runtime.h>

#define NNODES 50000
#define NEDGES 400000
#define NMOLS  2000
#define NBLK   196   // ceil(NNODES/256)

// ---- ws layout (4-byte units), total 9,350,256 * 4B = 37.4 MB ----
constexpr size_t OFF_CNT   = 0;         // 50000 int (zeroed each call by k_zero)
constexpr size_t OFF_OFFS  = 50000;     // 50000 int
constexpr size_t OFF_CURS  = 100000;    // 50000 int
constexpr size_t OFF_BSUM  = 150000;    // 256 int
constexpr size_t OFF_SRCS  = 150256;    // 400000 int (CSR-ordered src)
constexpr size_t OFF_EB4   = 550256;    // 400000*4 floats (dx,dy,dz,w0), 16B rows
constexpr size_t OFF_GB    = 2150256;   // 50000*16 uints (26 bf16 + pad = 64B rows)
constexpr size_t OFF_AB    = 2950256;   // 50000*32 uints (54 bf16 + pad = 128B rows)
constexpr size_t OFF_TB    = 4550256;   // 50000*80 uints (144 bf16 packed, 320B rows)
constexpr size_t OFF_HH    = 8550256;   // 50000*16 floats (9 used, 64B rows)
// end: 9,350,256

__device__ __forceinline__ unsigned short f2bf(float f) {
  unsigned int b = __float_as_uint(f);
  unsigned int r = (b + 0x7FFFu + ((b >> 16) & 1u)) >> 16;  // RNE
  return (unsigned short)r;
}
__device__ __forceinline__ float bflo(unsigned int u) { return __uint_as_float(u << 16); }
__device__ __forceinline__ float bfhi(unsigned int u) { return __uint_as_float(u & 0xFFFF0000u); }
__device__ __forceinline__ unsigned int packbf(float a, float b) {
  return (unsigned int)f2bf(a) | ((unsigned int)f2bf(b) << 16);
}

__device__ __forceinline__ void make_b(float w0, float dx, float dy, float dz, float* b) {
  const float s3 = 1.7320508075688772f, s5c = 2.2360679774997896f, s15 = 3.872983346207417f;
  float r2 = dx * dx + dy * dy + dz * dz;
  b[0] = w0;
  b[1] = w0 * s3 * dy;
  b[2] = w0 * s3 * dz;
  b[3] = w0 * s3 * dx;
  b[4] = w0 * s15 * dx * dy;
  b[5] = w0 * s15 * dy * dz;
  b[6] = w0 * 0.5f * s5c * (3.f * dz * dz - r2);
  b[7] = w0 * s15 * dx * dz;
  b[8] = w0 * 0.5f * s15 * (dx * dx - dy * dy);
}

// static-index access into uint4 Qv[18] (folds to a register after unroll)
#define TU(i) ((((i) & 3) == 0) ? Qv[(i) >> 2].x : (((i) & 3) == 1) ? Qv[(i) >> 2].y \
             : (((i) & 3) == 2) ? Qv[(i) >> 2].z : Qv[(i) >> 2].w)

// ---------- zero cnt + out in ONE launch (replaces two tiny hipMemsetAsync,
// each of which cost ~42us of pure dispatch overhead per round-11 profile) ----------
__global__ void k_zero(int* __restrict__ cnt, float* __restrict__ out, int out_n) {
  int i = blockIdx.x * blockDim.x + threadIdx.x;
  if (i < NNODES) cnt[i] = 0;
  if (i < out_n) out[i] = 0.f;
}

// ---------- CSR build ----------
__global__ void k_count(const int* __restrict__ dst, int* __restrict__ cnt) {
  int e = blockIdx.x * blockDim.x + threadIdx.x;
  if (e < NEDGES) atomicAdd(cnt + dst[e], 1);
}

__global__ void k_scanA(const int* __restrict__ cnt, int* __restrict__ offs, int* __restrict__ bsum) {
  __shared__ int sh[256];
  int t = threadIdx.x, i = blockIdx.x * 256 + t;
  int c = (i < NNODES) ? cnt[i] : 0;
  sh[t] = c; __syncthreads();
  #pragma unroll
  for (int off = 1; off < 256; off <<= 1) {
    int v = (t >= off) ? sh[t - off] : 0; __syncthreads();
    sh[t] += v; __syncthreads();
  }
  if (i < NNODES) offs[i] = sh[t] - c;
  if (t == 255) bsum[blockIdx.x] = sh[255];
}

__global__ void k_scanB(int* __restrict__ bsum) {
  __shared__ int sh[256];
  int t = threadIdx.x;
  int v = (t < NBLK) ? bsum[t] : 0;
  sh[t] = v; __syncthreads();
  #pragma unroll
  for (int off = 1; off < 256; off <<= 1) {
    int u = (t >= off) ? sh[t - off] : 0; __syncthreads();
    sh[t] += u; __syncthreads();
  }
  bsum[t] = sh[t] - v;
}

__global__ void k_scanC(int* __restrict__ offs, int* __restrict__ curs, const int* __restrict__ bsum) {
  int i = blockIdx.x * 256 + threadIdx.x;
  if (i < NNODES) {
    int o = offs[i] + bsum[blockIdx.x];
    offs[i] = o;
    curs[i] = o;
  }
}

__global__ void k_fill(const float* __restrict__ pos, const float* __restrict__ ea,
                       const int* __restrict__ src, const int* __restrict__ dst,
                       int* __restrict__ curs, int* __restrict__ srcs, float4* __restrict__ eb4) {
  int e = blockIdx.x * blockDim.x + threadIdx.x;
  if (e >= NEDGES) return;
  int s = src[e], d = dst[e];
  int p = atomicAdd(curs + d, 1);
  srcs[p] = s;
  float dx = pos[3 * s] - pos[3 * d];
  float dy = pos[3 * s + 1] - pos[3 * d + 1];
  float dz = pos[3 * s + 2] - pos[3 * d + 2];
  eb4[p] = make_float4(dx, dy, dz, ea[(size_t)e * 7]);
}

// ---------- node linear + TP1 precompute (bf16-packed g, one 64B line/row) ----------
__global__ void __launch_bounds__(256, 2)
k_node1(const float* __restrict__ x, const float* __restrict__ lw,
        const float* __restrict__ lb, const float* __restrict__ w1,
        unsigned int* __restrict__ gb) {
  int n = blockIdx.x * blockDim.x + threadIdx.x;
  if (n >= NNODES) return;
  float f[23];
  const float* xr = x + (size_t)n * 23;
  #pragma unroll
  for (int v = 0; v < 23; ++v) {
    float acc = lb[v];
    const float* wr = lw + v * 23;
    #pragma unroll
    for (int c = 0; c < 23; ++c) acc += xr[c] * wr[c];
    f[v] = fmaxf(acc, 0.f);
  }
  float G[26];
  #pragma unroll
  for (int w = 0; w < 16; ++w) { float a = 0; for (int v = 0; v < 23; ++v) a += f[v] * w1[v * 16 + w]; G[w] = a; }
  #pragma unroll
  for (int w = 0; w < 6;  ++w) { float a = 0; for (int v = 0; v < 23; ++v) a += f[v] * w1[368 + v * 6 + w]; G[16 + w] = a; }
  #pragma unroll
  for (int w = 0; w < 4;  ++w) { float a = 0; for (int v = 0; v < 23; ++v) a += f[v] * w1[506 + v * 4 + w]; G[22 + w] = a; }
  unsigned int U[16];
  #pragma unroll
  for (int i = 0; i < 13; ++i) U[i] = packbf(G[2 * i], G[2 * i + 1]);
  U[13] = U[14] = U[15] = 0u;
  uint4* o = (uint4*)(gb + (size_t)n * 16);
  o[0] = make_uint4(U[0], U[1], U[2], U[3]);
  o[1] = make_uint4(U[4], U[5], U[6], U[7]);
  o[2] = make_uint4(U[8], U[9], U[10], U[11]);
  o[3] = make_uint4(U[12], U[13], U[14], U[15]);
}

// ---------- layer 1 gather: 8 lanes per node; writes bf16 A-row (128B) ----------
__global__ void __launch_bounds__(256, 2)
k_gather1(const int* __restrict__ offs, const int* __restrict__ cnt,
          const int* __restrict__ srcs, const float4* __restrict__ eb4,
          const unsigned int* __restrict__ gb, unsigned int* __restrict__ ab) {
  int tid = blockIdx.x * 256 + threadIdx.x;
  int n = tid >> 3, sl = tid & 7;
  if (n >= NNODES) return;
  int beg = offs[n], cn = cnt[n];
  float M[54];
  #pragma unroll
  for (int i = 0; i < 54; ++i) M[i] = 0.f;
  for (int j = sl; j < cn; j += 8) {
    int p = beg + j;
    int s = srcs[p];
    float4 ebv = eb4[p];
    float bb[9]; make_b(ebv.w, ebv.x, ebv.y, ebv.z, bb);
    const uint4* Gf = (const uint4*)(gb + (size_t)s * 16);
    uint4 u0 = Gf[0], u1 = Gf[1], u2 = Gf[2], u3 = Gf[3];
    unsigned int U[13] = { u0.x, u0.y, u0.z, u0.w, u1.x, u1.y, u1.z, u1.w,
                           u2.x, u2.y, u2.z, u2.w, u3.x };
    #pragma unroll
    for (int u = 0; u < 16; ++u) {
      float gv = (u & 1) ? bfhi(U[u >> 1]) : bflo(U[u >> 1]);
      M[u] += bb[0] * gv;
    }
    #pragma unroll
    for (int u = 0; u < 6; ++u) {
      int idx = 16 + u;
      float gv = (idx & 1) ? bfhi(U[idx >> 1]) : bflo(U[idx >> 1]);
      #pragma unroll
      for (int k = 0; k < 3; ++k) M[16 + 3 * u + k] += bb[1 + k] * gv;
    }
    #pragma unroll
    for (int u = 0; u < 4; ++u) {
      int idx = 22 + u;
      float gv = (idx & 1) ? bfhi(U[idx >> 1]) : bflo(U[idx >> 1]);
      #pragma unroll
      for (int K = 0; K < 5; ++K) M[34 + 5 * u + K] += bb[4 + K] * gv;
    }
  }
  #pragma unroll
  for (int m = 1; m < 8; m <<= 1)
    #pragma unroll
    for (int i = 0; i < 54; ++i) M[i] += __shfl_xor(M[i], m);
  if (sl == 0) {
    const float S23 = 0.20851441405707477f;
    float sc = S23 * rsqrtf((float)cn);
    unsigned int U[32];
    #pragma unroll
    for (int i = 0; i < 27; ++i) U[i] = packbf(sc * M[2 * i], sc * M[2 * i + 1]);
    #pragma unroll
    for (int i = 27; i < 32; ++i) U[i] = 0u;
    uint4* o4 = (uint4*)(ab + (size_t)n * 32);
    #pragma unroll
    for (int q = 0; q < 8; ++q)
      o4[q] = make_uint4(U[4 * q], U[4 * q + 1], U[4 * q + 2], U[4 * q + 3]);
  }
}

// ---------- TP2 stage A: per-node t from bf16 A-row, bf16-packed consumption order ----------
__global__ void __launch_bounds__(256, 2)
k_node2t(const unsigned int* __restrict__ ab, const float* __restrict__ w2,
         unsigned int* __restrict__ tb) {
  __shared__ float W[596];
  for (int i = threadIdx.x; i < 596; i += 256) W[i] = w2[i];
  __syncthreads();
  int n = blockIdx.x * 256 + threadIdx.x;
  if (n >= NNODES) return;
  float A[54];
  {
    const uint4* Af = (const uint4*)(ab + (size_t)n * 32);
    uint4 q0 = Af[0], q1 = Af[1], q2 = Af[2], q3 = Af[3], q4 = Af[4], q5 = Af[5], q6 = Af[6];
    unsigned int U[27] = { q0.x, q0.y, q0.z, q0.w, q1.x, q1.y, q1.z, q1.w,
                           q2.x, q2.y, q2.z, q2.w, q3.x, q3.y, q3.z, q3.w,
                           q4.x, q4.y, q4.z, q4.w, q5.x, q5.y, q5.z, q5.w,
                           q6.x, q6.y, q6.z };
    #pragma unroll
    for (int i = 0; i < 27; ++i) { A[2 * i] = bflo(U[i]); A[2 * i + 1] = bfhi(U[i]); }
  }

  unsigned int U[72];
  // O0 groups
  #pragma unroll
  for (int w = 0; w < 8; ++w) {
    float s0 = 0;
    #pragma unroll
    for (int u = 0; u < 16; ++u) s0 += A[u] * W[u * 8 + w];
    float p2[3];
    #pragma unroll
    for (int k = 0; k < 3; ++k) { float s = 0; for (int u = 0; u < 6; ++u) s += A[16 + 3 * u + k] * W[316 + 8 * u + w]; p2[k] = s; }
    float q3[5];
    #pragma unroll
    for (int K = 0; K < 5; ++K) { float s = 0; for (int u = 0; u < 4; ++u) s += A[34 + 5 * u + K] * W[472 + 8 * u + w]; q3[K] = s; }
    U[5 * w + 0] = packbf(s0, p2[0]);
    U[5 * w + 1] = packbf(p2[1], p2[2]);
    U[5 * w + 2] = packbf(q3[0], q3[1]);
    U[5 * w + 3] = packbf(q3[2], q3[3]);
    U[5 * w + 4] = packbf(q3[4], 0.f);
  }
  // O2 groups
  #pragma unroll
  for (int w = 0; w < 3; ++w) {
    float s1 = 0;
    #pragma unroll
    for (int u = 0; u < 16; ++u) s1 += A[u] * W[128 + 3 * u + w];
    float p1[3], p4[3];
    #pragma unroll
    for (int k = 0; k < 3; ++k) {
      float a = 0, c = 0;
      #pragma unroll
      for (int u = 0; u < 6; ++u) {
        a += A[16 + 3 * u + k] * W[298 + 3 * u + w];
        c += A[16 + 3 * u + k] * W[394 + 3 * u + w];
      }
      p1[k] = a; p4[k] = c;
    }
    float q2[5];
    #pragma unroll
    for (int K = 0; K < 5; ++K) { float s = 0; for (int u = 0; u < 4; ++u) s += A[34 + 5 * u + K] * W[444 + 3 * u + w]; q2[K] = s; }
    int base = 40 + 6 * w;
    U[base + 0] = packbf(s1, p1[0]);
    U[base + 1] = packbf(p1[1], p1[2]);
    U[base + 2] = packbf(p4[0], p4[1]);
    U[base + 3] = packbf(p4[2], q2[0]);
    U[base + 4] = packbf(q2[1], q2[2]);
    U[base + 5] = packbf(q2[3], q2[4]);
  }
  // O3 groups
  #pragma unroll
  for (int w = 0; w < 2; ++w) {
    float s2 = 0;
    #pragma unroll
    for (int u = 0; u < 16; ++u) s2 += A[u] * W[176 + 2 * u + w];
    float q1[5], q4[5];
    #pragma unroll
    for (int K = 0; K < 5; ++K) {
      float a = 0, c = 0;
      #pragma unroll
      for (int u = 0; u < 4; ++u) {
        a += A[34 + 5 * u + K] * W[436 + 2 * u + w];
        c += A[34 + 5 * u + K] * W[516 + 2 * u + w];
      }
      q1[K] = a; q4[K] = c;
    }
    float p3[3];
    #pragma unroll
    for (int k = 0; k < 3; ++k) { float s = 0; for (int u = 0; u < 6; ++u) s += A[16 + 3 * u + k] * W[382 + 2 * u + w]; p3[k] = s; }
    int base = 58 + 7 * w;
    U[base + 0] = packbf(s2, q1[0]);
    U[base + 1] = packbf(q1[1], q1[2]);
    U[base + 2] = packbf(q1[3], q1[4]);
    U[base + 3] = packbf(p3[0], p3[1]);
    U[base + 4] = packbf(p3[2], q4[0]);
    U[base + 5] = packbf(q4[1], q4[2]);
    U[base + 6] = packbf(q4[3], q4[4]);
  }
  uint4* o = (uint4*)(tb + (size_t)n * 80);
  #pragma unroll
  for (int q = 0; q < 18; ++q)
    o[q] = make_uint4(U[4 * q], U[4 * q + 1], U[4 * q + 2], U[4 * q + 3]);
}

// ---------- TP2 stage B: edge combine — NO TT staging copy (direct Qv access), 128-VGPR cap ----------
__global__ void __launch_bounds__(256, 2)
k_edge2c(const int* __restrict__ offs, const int* __restrict__ cnt,
         const int* __restrict__ srcs, const float4* __restrict__ eb4,
         const unsigned int* __restrict__ tb, const float* __restrict__ w3,
         float* __restrict__ hh) {
  int tid = blockIdx.x * 256 + threadIdx.x;
  int n = tid >> 3, sl = tid & 7;
  if (n >= NNODES) return;
  int beg = offs[n], cn = cnt[n];
  float O0[8], O2[9], O3[10];
  #pragma unroll
  for (int i = 0; i < 8; ++i) O0[i] = 0.f;
  #pragma unroll
  for (int i = 0; i < 9; ++i) O2[i] = 0.f;
  #pragma unroll
  for (int i = 0; i < 10; ++i) O3[i] = 0.f;

  const float I3 = 0.5773502691896258f, I5 = 0.4472135954999579f;
  const float CA = 0.18257418583505536f, CB = 0.31622776601683794f, CC = 0.3651483716701107f;
  const float P = 0.2390457218668787f, Q = 0.2070196678027063f, R = 0.1195228609334394f;

  for (int j = sl; j < cn; j += 8) {
    int p = beg + j;
    int s = srcs[p];
    const uint4* T4 = (const uint4*)(tb + (size_t)s * 80);
    uint4 Qv[18];
    #pragma unroll
    for (int i = 0; i < 18; ++i) Qv[i] = T4[i];
    float4 ebv = eb4[p];
    float b[9]; make_b(ebv.w, ebv.x, ebv.y, ebv.z, b);

    // O0 (8 groups @ 5 uints, base 5w)
    #pragma unroll
    for (int w = 0; w < 8; ++w) {
      unsigned int u0 = TU(5 * w), u1 = TU(5 * w + 1), u2 = TU(5 * w + 2),
                   u3 = TU(5 * w + 3), u4 = TU(5 * w + 4);
      O0[w] += b[0] * bflo(u0)
             + I3 * (bfhi(u0) * b[1] + bflo(u1) * b[2] + bfhi(u1) * b[3])
             + I5 * (bflo(u2) * b[4] + bfhi(u2) * b[5] + bflo(u3) * b[6]
                   + bfhi(u3) * b[7] + bflo(u4) * b[8]);
    }
    // O2 (3 groups @ 6 uints, base 40+6w)
    #pragma unroll
    for (int w = 0; w < 3; ++w) {
      unsigned int u0 = TU(40 + 6 * w), u1 = TU(41 + 6 * w), u2 = TU(42 + 6 * w),
                   u3 = TU(43 + 6 * w), u4 = TU(44 + 6 * w), u5 = TU(45 + 6 * w);
      float ta  = bflo(u0);
      float tb0 = bfhi(u0), tb1 = bflo(u1), tb2 = bfhi(u1);
      float tc0 = bflo(u2), tc1 = bfhi(u2), tc2 = bflo(u3);
      float td0 = bfhi(u3), td1 = bflo(u4), td2 = bfhi(u4), td3 = bflo(u5), td4 = bfhi(u5);
      O2[3 * w + 0] += I3 * (b[1] * ta + b[0] * tb0)
                     + tc0 * (-CA * b[6] - CB * b[8]) + tc1 * (CB * b[5]) + tc2 * (CB * b[4])
                     + td0 * (CB * b[3]) + td1 * (CB * b[2]) - td2 * (CA * b[1]) - td4 * (CB * b[1]);
      O2[3 * w + 1] += I3 * (b[2] * ta + b[0] * tb1)
                     + tc0 * (CB * b[5]) + tc1 * (CC * b[6]) + tc2 * (CB * b[7])
                     + td1 * (CB * b[1]) + td2 * (CC * b[2]) + td3 * (CB * b[3]);
      O2[3 * w + 2] += I3 * (b[3] * ta + b[0] * tb2)
                     + tc0 * (CB * b[4]) + tc1 * (CB * b[7]) + tc2 * (-CA * b[6] + CB * b[8])
                     + td0 * (CB * b[1]) - td2 * (CA * b[3]) + td3 * (CB * b[2]) + td4 * (CB * b[3]);
    }
    // O3 (2 groups @ 7 uints, base 58+7w)
    #pragma unroll
    for (int w = 0; w < 2; ++w) {
      unsigned int u0 = TU(58 + 7 * w), u1 = TU(59 + 7 * w), u2 = TU(60 + 7 * w),
                   u3 = TU(61 + 7 * w), u4 = TU(62 + 7 * w), u5 = TU(63 + 7 * w),
                   u6 = TU(64 + 7 * w);
      float ta  = bflo(u0);
      float tb0 = bfhi(u0), tb1 = bflo(u1), tb2 = bfhi(u1), tb3 = bflo(u2), tb4 = bfhi(u2);
      float tc0 = bflo(u3), tc1 = bfhi(u3), tc2 = bflo(u4);
      float td0 = bfhi(u4), td1 = bflo(u5), td2 = bfhi(u5), td3 = bflo(u6), td4 = bfhi(u6);
      O3[5 * w + 0] += I5 * (b[4] * ta + b[0] * tb0)
                     + tc0 * (CB * b[3]) + tc2 * (CB * b[1])
                     - (P * b[6]) * td0 + (Q * b[7]) * td1 - (P * b[4]) * td2 + (Q * b[5]) * td3;
      O3[5 * w + 1] += I5 * (b[5] * ta + b[0] * tb1)
                     + tc0 * (CB * b[2]) + tc1 * (CB * b[1])
                     + (Q * b[7]) * td0 + (R * b[6] - Q * b[8]) * td1 + (R * b[5]) * td2
                     + (Q * b[4]) * td3 - (Q * b[5]) * td4;
      O3[5 * w + 2] += I5 * (b[6] * ta + b[0] * tb2)
                     - tc0 * (CA * b[1]) + tc1 * (CC * b[2]) - tc2 * (CA * b[3])
                     - (P * b[4]) * td0 + (R * b[5]) * td1 + (P * b[6]) * td2
                     + (R * b[7]) * td3 - (P * b[8]) * td4;
      O3[5 * w + 3] += I5 * (b[7] * ta + b[0] * tb3)
                     + tc1 * (CB * b[3]) + tc2 * (CB * b[2])
                     + (Q * b[5]) * td0 + (Q * b[4]) * td1 + (R * b[7]) * td2
                     + (R * b[6] + Q * b[8]) * td3 + (Q * b[7]) * td4;
      O3[5 * w + 4] += I5 * (b[8] * ta + b[0] * tb4)
                     - tc0 * (CB * b[1]) + tc2 * (CB * b[3])
                     - (Q * b[5]) * td1 - (P * b[8]) * td2 + (Q * b[7]) * td3 - (P * b[6]) * td4;
    }
  }

  #pragma unroll
  for (int m = 1; m < 8; m <<= 1) {
    #pragma unroll
    for (int i = 0; i < 8; ++i) O0[i] += __shfl_xor(O0[i], m);
    #pragma unroll
    for (int i = 0; i < 9; ++i) O2[i] += __shfl_xor(O2[i], m);
    #pragma unroll
    for (int i = 0; i < 10; ++i) O3[i] += __shfl_xor(O3[i], m);
  }

  if (sl == 0) {
    const float S26 = 0.19611613513818404f, S14 = 0.2672612419124244f, S8 = 0.35355339059327373f;
    const float S13 = 0.2773500981126146f;
    float di = rsqrtf((float)cn);
    float F[27];
    #pragma unroll
    for (int w = 0; w < 8; ++w) F[w] = S26 * di * O0[w];
    #pragma unroll
    for (int i = 0; i < 9; ++i) F[8 + i] = S14 * di * O2[i];
    #pragma unroll
    for (int i = 0; i < 10; ++i) F[17 + i] = S8 * di * O3[i];

    float h[9];
    float t0 = 0;
    #pragma unroll
    for (int u = 0; u < 8; ++u) t0 += F[u] * w3[u];
    h[0] = S13 * t0;
    #pragma unroll
    for (int jj = 0; jj < 3; ++jj) {
      float s1 = 0;
      #pragma unroll
      for (int u = 0; u < 3; ++u) s1 += F[8 + 3 * u + jj] * w3[8 + u];
      h[1 + jj] = S13 * I3 * s1;
    }
    #pragma unroll
    for (int K = 0; K < 5; ++K)
      h[4 + K] = S13 * I5 * (F[17 + K] * w3[11] + F[22 + K] * w3[12]);

    float4* o4 = (float4*)(hh + (size_t)n * 16);
    o4[0] = make_float4(h[0], h[1], h[2], h[3]);
    o4[1] = make_float4(h[4], h[5], h[6], h[7]);
    o4[2] = make_float4(h[8], 0.f, 0.f, 0.f);
  }
}

// ---------- layer 3 gather + molecule reduce ----------
__global__ void k_gather3(const int* __restrict__ offs, const int* __restrict__ cnt,
                          const int* __restrict__ srcs, const float4* __restrict__ eb4,
                          const float* __restrict__ hh, const int* __restrict__ batch,
                          float* __restrict__ out) {
  int tid = blockIdx.x * 256 + threadIdx.x;
  int n = tid >> 3, sl = tid & 7;
  if (n >= NNODES) return;
  int beg = offs[n], cn = cnt[n];
  float v = 0.f;
  for (int j = sl; j < cn; j += 8) {
    int p = beg + j;
    int s = srcs[p];
    float4 ebv = eb4[p];
    float b[9]; make_b(ebv.w, ebv.x, ebv.y, ebv.z, b);
    const float4* Hf = (const float4*)(hh + (size_t)s * 16);
    float4 hA = Hf[0], hB = Hf[1];
    float h8 = Hf[2].x;
    v += b[0] * hA.x + b[1] * hA.y + b[2] * hA.z + b[3] * hA.w
       + b[4] * hB.x + b[5] * hB.y + b[6] * hB.z + b[7] * hB.w
       + b[8] * h8;
  }
  #pragma unroll
  for (int m = 1; m < 8; m <<= 1) v += __shfl_xor(v, m);
  if (sl == 0) {
    float di = rsqrtf((float)cn);
    unsafeAtomicAdd(out + batch[n], v * di * 0.2f);  // /sqrt(apm)=/5
  }
}

extern "C" void kernel_launch(void* const* d_in, const int* in_sizes, int n_in,
                              void* d_out, int out_size, void* d_ws, size_t ws_size,
                              hipStream_t stream) {
  const float* positions = (const float*)d_in[0];
  const float* x         = (const float*)d_in[1];
  const float* edge_attr = (const float*)d_in[2];
  const float* lin_w     = (const float*)d_in[3];
  const float* lin_b     = (const float*)d_in[4];
  const float* w_tp1     = (const float*)d_in[5];
  const float* w_tp2     = (const float*)d_in[6];
  const float* w_tp3     = (const float*)d_in[7];
  const int*   edge_src  = (const int*)d_in[8];
  const int*   edge_dst  = (const int*)d_in[9];
  const int*   batch     = (const int*)d_in[10];
  float* out = (float*)d_out;

  int*   cnt  = (int*)d_ws + OFF_CNT;
  int*   offs = (int*)d_ws + OFF_OFFS;
  int*   curs = (int*)d_ws + OFF_CURS;
  int*   bsum = (int*)d_ws + OFF_BSUM;
  int*   srcs = (int*)d_ws + OFF_SRCS;
  float4* eb4 = (float4*)((float*)d_ws + OFF_EB4);
  unsigned int* gb = (unsigned int*)((float*)d_ws + OFF_GB);
  unsigned int* ab = (unsigned int*)((float*)d_ws + OFF_AB);
  unsigned int* tb = (unsigned int*)((float*)d_ws + OFF_TB);
  float* hh   = (float*)d_ws + OFF_HH;

  dim3 blk256(256);
  dim3 gEdge((NEDGES + 255) / 256);
  dim3 gNode256((NNODES + 255) / 256);
  dim3 gCoop((NNODES * 8 + 255) / 256);

  k_zero<<<gNode256, blk256, 0, stream>>>(cnt, out, out_size);
  k_count<<<gEdge, blk256, 0, stream>>>(edge_dst, cnt);
  k_scanA<<<dim3(NBLK), blk256, 0, stream>>>(cnt, offs, bsum);
  k_scanB<<<dim3(1), blk256, 0, stream>>>(bsum);
  k_scanC<<<dim3(NBLK), blk256, 0, stream>>>(offs, curs, bsum);
  k_fill<<<gEdge, blk256, 0, stream>>>(positions, edge_attr, edge_src, edge_dst, curs, srcs, eb4);
  k_node1<<<gNode256, blk256, 0, stream>>>(x, lin_w, lin_b, w_tp1, gb);
  k_gather1<<<gCoop, blk256, 0, stream>>>(offs, cnt, srcs, eb4, gb, ab);
  k_node2t<<<gNode256, blk256, 0, stream>>>(ab, w_tp2, tb);
  k_edge2c<<<gCoop, blk256, 0, stream>>>(offs, cnt, srcs, eb4, tb, w_tp3, hh);
  k_gather3<<<gCoop, blk256, 0, stream>>>(offs, cnt, srcs, eb4, hh, batch, out);
}

// Round 14
// 150.589 us; speedup vs baseline: 5.2385x; 1.0921x over previous
//
#include <hip/hip_runtime.h>

#define NNODES 50000
#define NEDGES 400000
#define NMOLS  2000
#define NBLK   196   // ceil(NNODES/256)

// ---- ws layout (4-byte units), total 7,750,256 * 4B = 31 MB ----
constexpr size_t OFF_CNT   = 0;         // 50000 int (zeroed by k_prep)
constexpr size_t OFF_OFFS  = 50000;     // 50000 int
constexpr size_t OFF_CURS  = 100000;    // 50000 int
constexpr size_t OFF_BSUM  = 150000;    // 256 int
constexpr size_t OFF_SRCS  = 150256;    // 400000 int (CSR-ordered src)
constexpr size_t OFF_EB4   = 550256;    // 400000*4 floats (dx,dy,dz,w0), 16B rows
constexpr size_t OFF_GB    = 2150256;   // 50000*16 uints (26 bf16 + pad = 64B rows)
constexpr size_t OFF_TB    = 2950256;   // 50000*80 uints (144 bf16 packed, 320B rows)
constexpr size_t OFF_HH    = 6950256;   // 50000*16 floats (9 used, 64B rows)
// end: 7,750,256

__device__ __forceinline__ unsigned short f2bf(float f) {
  unsigned int b = __float_as_uint(f);
  unsigned int r = (b + 0x7FFFu + ((b >> 16) & 1u)) >> 16;  // RNE
  return (unsigned short)r;
}
__device__ __forceinline__ float bflo(unsigned int u) { return __uint_as_float(u << 16); }
__device__ __forceinline__ float bfhi(unsigned int u) { return __uint_as_float(u & 0xFFFF0000u); }
__device__ __forceinline__ unsigned int packbf(float a, float b) {
  return (unsigned int)f2bf(a) | ((unsigned int)f2bf(b) << 16);
}

__device__ __forceinline__ void make_b(float w0, float dx, float dy, float dz, float* b) {
  const float s3 = 1.7320508075688772f, s5c = 2.2360679774997896f, s15 = 3.872983346207417f;
  float r2 = dx * dx + dy * dy + dz * dz;
  b[0] = w0;
  b[1] = w0 * s3 * dy;
  b[2] = w0 * s3 * dz;
  b[3] = w0 * s3 * dx;
  b[4] = w0 * s15 * dx * dy;
  b[5] = w0 * s15 * dy * dz;
  b[6] = w0 * 0.5f * s5c * (3.f * dz * dz - r2);
  b[7] = w0 * s15 * dx * dz;
  b[8] = w0 * 0.5f * s15 * (dx * dx - dy * dy);
}

// static-index access into uint4 Qv[18] (folds to a register after unroll)
#define TU(i) ((((i) & 3) == 0) ? Qv[(i) >> 2].x : (((i) & 3) == 1) ? Qv[(i) >> 2].y \
             : (((i) & 3) == 2) ? Qv[(i) >> 2].z : Qv[(i) >> 2].w)

// ---------- k_prep: zero cnt/out + node linear + TP1 precompute (fused: both launch-independent) ----------
__global__ void __launch_bounds__(256, 2)
k_prep(const float* __restrict__ x, const float* __restrict__ lw,
       const float* __restrict__ lb, const float* __restrict__ w1,
       unsigned int* __restrict__ gb, int* __restrict__ cnt,
       float* __restrict__ out, int out_n) {
  int n = blockIdx.x * blockDim.x + threadIdx.x;
  if (n < NNODES) cnt[n] = 0;
  if (n < out_n) out[n] = 0.f;
  if (n >= NNODES) return;
  float f[23];
  const float* xr = x + (size_t)n * 23;
  #pragma unroll
  for (int v = 0; v < 23; ++v) {
    float acc = lb[v];
    const float* wr = lw + v * 23;
    #pragma unroll
    for (int c = 0; c < 23; ++c) acc += xr[c] * wr[c];
    f[v] = fmaxf(acc, 0.f);
  }
  float G[26];
  #pragma unroll
  for (int w = 0; w < 16; ++w) { float a = 0; for (int v = 0; v < 23; ++v) a += f[v] * w1[v * 16 + w]; G[w] = a; }
  #pragma unroll
  for (int w = 0; w < 6;  ++w) { float a = 0; for (int v = 0; v < 23; ++v) a += f[v] * w1[368 + v * 6 + w]; G[16 + w] = a; }
  #pragma unroll
  for (int w = 0; w < 4;  ++w) { float a = 0; for (int v = 0; v < 23; ++v) a += f[v] * w1[506 + v * 4 + w]; G[22 + w] = a; }
  unsigned int U[16];
  #pragma unroll
  for (int i = 0; i < 13; ++i) U[i] = packbf(G[2 * i], G[2 * i + 1]);
  U[13] = U[14] = U[15] = 0u;
  uint4* o = (uint4*)(gb + (size_t)n * 16);
  o[0] = make_uint4(U[0], U[1], U[2], U[3]);
  o[1] = make_uint4(U[4], U[5], U[6], U[7]);
  o[2] = make_uint4(U[8], U[9], U[10], U[11]);
  o[3] = make_uint4(U[12], U[13], U[14], U[15]);
}

// ---------- CSR build ----------
__global__ void k_count(const int* __restrict__ dst, int* __restrict__ cnt) {
  int e = blockIdx.x * blockDim.x + threadIdx.x;
  if (e < NEDGES) atomicAdd(cnt + dst[e], 1);
}

__global__ void k_scanA(const int* __restrict__ cnt, int* __restrict__ offs, int* __restrict__ bsum) {
  __shared__ int sh[256];
  int t = threadIdx.x, i = blockIdx.x * 256 + t;
  int c = (i < NNODES) ? cnt[i] : 0;
  sh[t] = c; __syncthreads();
  #pragma unroll
  for (int off = 1; off < 256; off <<= 1) {
    int v = (t >= off) ? sh[t - off] : 0; __syncthreads();
    sh[t] += v; __syncthreads();
  }
  if (i < NNODES) offs[i] = sh[t] - c;
  if (t == 255) bsum[blockIdx.x] = sh[255];
}

__global__ void k_scanB(int* __restrict__ bsum) {
  __shared__ int sh[256];
  int t = threadIdx.x;
  int v = (t < NBLK) ? bsum[t] : 0;
  sh[t] = v; __syncthreads();
  #pragma unroll
  for (int off = 1; off < 256; off <<= 1) {
    int u = (t >= off) ? sh[t - off] : 0; __syncthreads();
    sh[t] += u; __syncthreads();
  }
  bsum[t] = sh[t] - v;
}

__global__ void k_scanC(int* __restrict__ offs, int* __restrict__ curs, const int* __restrict__ bsum) {
  int i = blockIdx.x * 256 + threadIdx.x;
  if (i < NNODES) {
    int o = offs[i] + bsum[blockIdx.x];
    offs[i] = o;
    curs[i] = o;
  }
}

__global__ void k_fill(const float* __restrict__ pos, const float* __restrict__ ea,
                       const int* __restrict__ src, const int* __restrict__ dst,
                       int* __restrict__ curs, int* __restrict__ srcs, float4* __restrict__ eb4) {
  int e = blockIdx.x * blockDim.x + threadIdx.x;
  if (e >= NEDGES) return;
  int s = src[e], d = dst[e];
  int p = atomicAdd(curs + d, 1);
  srcs[p] = s;
  float dx = pos[3 * s] - pos[3 * d];
  float dy = pos[3 * s + 1] - pos[3 * d + 1];
  float dz = pos[3 * s + 2] - pos[3 * d + 2];
  eb4[p] = make_float4(dx, dy, dz, ea[(size_t)e * 7]);
}

// ---------- layer 1 gather FUSED with TP2 stage A: 8 lanes per node; writes bf16 t-row (320B) ----------
// After butterfly all 8 lanes hold full fp32 M[54]; lanes statically split the 13 t-groups:
// lane sl: O0 group w=sl (5 uints @5sl); lanes 0-2: O2 group w=sl (6 uints @40+6sl);
// lanes 3-4: O3 group w=sl-3 (7 uints @58+7(sl-3)).
__global__ void __launch_bounds__(256, 2)
k_gather1t(const int* __restrict__ offs, const int* __restrict__ cnt,
           const int* __restrict__ srcs, const float4* __restrict__ eb4,
           const unsigned int* __restrict__ gb, const float* __restrict__ w2,
           unsigned int* __restrict__ tb) {
  __shared__ float W[596];
  for (int i = threadIdx.x; i < 596; i += 256) W[i] = w2[i];
  __syncthreads();
  int tid = blockIdx.x * 256 + threadIdx.x;
  int n = tid >> 3, sl = tid & 7;
  if (n >= NNODES) return;
  int beg = offs[n], cn = cnt[n];
  float M[54];
  #pragma unroll
  for (int i = 0; i < 54; ++i) M[i] = 0.f;
  for (int j = sl; j < cn; j += 8) {
    int p = beg + j;
    int s = srcs[p];
    float4 ebv = eb4[p];
    float bb[9]; make_b(ebv.w, ebv.x, ebv.y, ebv.z, bb);
    const uint4* Gf = (const uint4*)(gb + (size_t)s * 16);
    uint4 u0 = Gf[0], u1 = Gf[1], u2 = Gf[2], u3 = Gf[3];
    unsigned int U[13] = { u0.x, u0.y, u0.z, u0.w, u1.x, u1.y, u1.z, u1.w,
                           u2.x, u2.y, u2.z, u2.w, u3.x };
    #pragma unroll
    for (int u = 0; u < 16; ++u) {
      float gv = (u & 1) ? bfhi(U[u >> 1]) : bflo(U[u >> 1]);
      M[u] += bb[0] * gv;
    }
    #pragma unroll
    for (int u = 0; u < 6; ++u) {
      int idx = 16 + u;
      float gv = (idx & 1) ? bfhi(U[idx >> 1]) : bflo(U[idx >> 1]);
      #pragma unroll
      for (int k = 0; k < 3; ++k) M[16 + 3 * u + k] += bb[1 + k] * gv;
    }
    #pragma unroll
    for (int u = 0; u < 4; ++u) {
      int idx = 22 + u;
      float gv = (idx & 1) ? bfhi(U[idx >> 1]) : bflo(U[idx >> 1]);
      #pragma unroll
      for (int K = 0; K < 5; ++K) M[34 + 5 * u + K] += bb[4 + K] * gv;
    }
  }
  #pragma unroll
  for (int m = 1; m < 8; m <<= 1)
    #pragma unroll
    for (int i = 0; i < 54; ++i) M[i] += __shfl_xor(M[i], m);

  // A = S23 * dis * M, fp32 (no intermediate bf16 rounding of A anymore)
  const float S23 = 0.20851441405707477f;
  float sc = S23 * rsqrtf((float)cn);
  #pragma unroll
  for (int i = 0; i < 54; ++i) M[i] *= sc;

  unsigned int* trow = tb + (size_t)n * 80;
  // ---- O0 group w = sl (all 8 lanes) ----
  {
    int w = sl;
    float s0 = 0;
    #pragma unroll
    for (int u = 0; u < 16; ++u) s0 += M[u] * W[u * 8 + w];
    float p2[3];
    #pragma unroll
    for (int k = 0; k < 3; ++k) { float s = 0; for (int u = 0; u < 6; ++u) s += M[16 + 3 * u + k] * W[316 + 8 * u + w]; p2[k] = s; }
    float q3[5];
    #pragma unroll
    for (int K = 0; K < 5; ++K) { float s = 0; for (int u = 0; u < 4; ++u) s += M[34 + 5 * u + K] * W[472 + 8 * u + w]; q3[K] = s; }
    trow[5 * w + 0] = packbf(s0, p2[0]);
    trow[5 * w + 1] = packbf(p2[1], p2[2]);
    trow[5 * w + 2] = packbf(q3[0], q3[1]);
    trow[5 * w + 3] = packbf(q3[2], q3[3]);
    trow[5 * w + 4] = packbf(q3[4], 0.f);
  }
  // ---- O2 groups: lanes 0-2 ----
  if (sl < 3) {
    int w = sl;
    float s1 = 0;
    #pragma unroll
    for (int u = 0; u < 16; ++u) s1 += M[u] * W[128 + 3 * u + w];
    float p1[3], p4[3];
    #pragma unroll
    for (int k = 0; k < 3; ++k) {
      float a = 0, c = 0;
      #pragma unroll
      for (int u = 0; u < 6; ++u) {
        a += M[16 + 3 * u + k] * W[298 + 3 * u + w];
        c += M[16 + 3 * u + k] * W[394 + 3 * u + w];
      }
      p1[k] = a; p4[k] = c;
    }
    float q2[5];
    #pragma unroll
    for (int K = 0; K < 5; ++K) { float s = 0; for (int u = 0; u < 4; ++u) s += M[34 + 5 * u + K] * W[444 + 3 * u + w]; q2[K] = s; }
    int base = 40 + 6 * w;
    trow[base + 0] = packbf(s1, p1[0]);
    trow[base + 1] = packbf(p1[1], p1[2]);
    trow[base + 2] = packbf(p4[0], p4[1]);
    trow[base + 3] = packbf(p4[2], q2[0]);
    trow[base + 4] = packbf(q2[1], q2[2]);
    trow[base + 5] = packbf(q2[3], q2[4]);
  } else if (sl < 5) {
    // ---- O3 groups: lanes 3-4 ----
    int w = sl - 3;
    float s2 = 0;
    #pragma unroll
    for (int u = 0; u < 16; ++u) s2 += M[u] * W[176 + 2 * u + w];
    float q1[5], q4[5];
    #pragma unroll
    for (int K = 0; K < 5; ++K) {
      float a = 0, c = 0;
      #pragma unroll
      for (int u = 0; u < 4; ++u) {
        a += M[34 + 5 * u + K] * W[436 + 2 * u + w];
        c += M[34 + 5 * u + K] * W[516 + 2 * u + w];
      }
      q1[K] = a; q4[K] = c;
    }
    float p3[3];
    #pragma unroll
    for (int k = 0; k < 3; ++k) { float s = 0; for (int u = 0; u < 6; ++u) s += M[16 + 3 * u + k] * W[382 + 2 * u + w]; p3[k] = s; }
    int base = 58 + 7 * w;
    trow[base + 0] = packbf(s2, q1[0]);
    trow[base + 1] = packbf(q1[1], q1[2]);
    trow[base + 2] = packbf(q1[3], q1[4]);
    trow[base + 3] = packbf(p3[0], p3[1]);
    trow[base + 4] = packbf(p3[2], q4[0]);
    trow[base + 5] = packbf(q4[1], q4[2]);
    trow[base + 6] = packbf(q4[3], q4[4]);
  }
}

// ---------- TP2 stage B: edge combine (direct Qv access, no staging copy) + TP3 precompute ----------
__global__ void __launch_bounds__(256, 2)
k_edge2c(const int* __restrict__ offs, const int* __restrict__ cnt,
         const int* __restrict__ srcs, const float4* __restrict__ eb4,
         const unsigned int* __restrict__ tb, const float* __restrict__ w3,
         float* __restrict__ hh) {
  int tid = blockIdx.x * 256 + threadIdx.x;
  int n = tid >> 3, sl = tid & 7;
  if (n >= NNODES) return;
  int beg = offs[n], cn = cnt[n];
  float O0[8], O2[9], O3[10];
  #pragma unroll
  for (int i = 0; i < 8; ++i) O0[i] = 0.f;
  #pragma unroll
  for (int i = 0; i < 9; ++i) O2[i] = 0.f;
  #pragma unroll
  for (int i = 0; i < 10; ++i) O3[i] = 0.f;

  const float I3 = 0.5773502691896258f, I5 = 0.4472135954999579f;
  const float CA = 0.18257418583505536f, CB = 0.31622776601683794f, CC = 0.3651483716701107f;
  const float P = 0.2390457218668787f, Q = 0.2070196678027063f, R = 0.1195228609334394f;

  for (int j = sl; j < cn; j += 8) {
    int p = beg + j;
    int s = srcs[p];
    const uint4* T4 = (const uint4*)(tb + (size_t)s * 80);
    uint4 Qv[18];
    #pragma unroll
    for (int i = 0; i < 18; ++i) Qv[i] = T4[i];
    float4 ebv = eb4[p];
    float b[9]; make_b(ebv.w, ebv.x, ebv.y, ebv.z, b);

    // O0 (8 groups @ 5 uints, base 5w)
    #pragma unroll
    for (int w = 0; w < 8; ++w) {
      unsigned int u0 = TU(5 * w), u1 = TU(5 * w + 1), u2 = TU(5 * w + 2),
                   u3 = TU(5 * w + 3), u4 = TU(5 * w + 4);
      O0[w] += b[0] * bflo(u0)
             + I3 * (bfhi(u0) * b[1] + bflo(u1) * b[2] + bfhi(u1) * b[3])
             + I5 * (bflo(u2) * b[4] + bfhi(u2) * b[5] + bflo(u3) * b[6]
                   + bfhi(u3) * b[7] + bflo(u4) * b[8]);
    }
    // O2 (3 groups @ 6 uints, base 40+6w)
    #pragma unroll
    for (int w = 0; w < 3; ++w) {
      unsigned int u0 = TU(40 + 6 * w), u1 = TU(41 + 6 * w), u2 = TU(42 + 6 * w),
                   u3 = TU(43 + 6 * w), u4 = TU(44 + 6 * w), u5 = TU(45 + 6 * w);
      float ta  = bflo(u0);
      float tb0 = bfhi(u0), tb1 = bflo(u1), tb2 = bfhi(u1);
      float tc0 = bflo(u2), tc1 = bfhi(u2), tc2 = bflo(u3);
      float td0 = bfhi(u3), td1 = bflo(u4), td2 = bfhi(u4), td3 = bflo(u5), td4 = bfhi(u5);
      O2[3 * w + 0] += I3 * (b[1] * ta + b[0] * tb0)
                     + tc0 * (-CA * b[6] - CB * b[8]) + tc1 * (CB * b[5]) + tc2 * (CB * b[4])
                     + td0 * (CB * b[3]) + td1 * (CB * b[2]) - td2 * (CA * b[1]) - td4 * (CB * b[1]);
      O2[3 * w + 1] += I3 * (b[2] * ta + b[0] * tb1)
                     + tc0 * (CB * b[5]) + tc1 * (CC * b[6]) + tc2 * (CB * b[7])
                     + td1 * (CB * b[1]) + td2 * (CC * b[2]) + td3 * (CB * b[3]);
      O2[3 * w + 2] += I3 * (b[3] * ta + b[0] * tb2)
                     + tc0 * (CB * b[4]) + tc1 * (CB * b[7]) + tc2 * (-CA * b[6] + CB * b[8])
                     + td0 * (CB * b[1]) - td2 * (CA * b[3]) + td3 * (CB * b[2]) + td4 * (CB * b[3]);
    }
    // O3 (2 groups @ 7 uints, base 58+7w)
    #pragma unroll
    for (int w = 0; w < 2; ++w) {
      unsigned int u0 = TU(58 + 7 * w), u1 = TU(59 + 7 * w), u2 = TU(60 + 7 * w),
                   u3 = TU(61 + 7 * w), u4 = TU(62 + 7 * w), u5 = TU(63 + 7 * w),
                   u6 = TU(64 + 7 * w);
      float ta  = bflo(u0);
      float tb0 = bfhi(u0), tb1 = bflo(u1), tb2 = bfhi(u1), tb3 = bflo(u2), tb4 = bfhi(u2);
      float tc0 = bflo(u3), tc1 = bfhi(u3), tc2 = bflo(u4);
      float td0 = bfhi(u4), td1 = bflo(u5), td2 = bfhi(u5), td3 = bflo(u6), td4 = bfhi(u6);
      O3[5 * w + 0] += I5 * (b[4] * ta + b[0] * tb0)
                     + tc0 * (CB * b[3]) + tc2 * (CB * b[1])
                     - (P * b[6]) * td0 + (Q * b[7]) * td1 - (P * b[4]) * td2 + (Q * b[5]) * td3;
      O3[5 * w + 1] += I5 * (b[5] * ta + b[0] * tb1)
                     + tc0 * (CB * b[2]) + tc1 * (CB * b[1])
                     + (Q * b[7]) * td0 + (R * b[6] - Q * b[8]) * td1 + (R * b[5]) * td2
                     + (Q * b[4]) * td3 - (Q * b[5]) * td4;
      O3[5 * w + 2] += I5 * (b[6] * ta + b[0] * tb2)
                     - tc0 * (CA * b[1]) + tc1 * (CC * b[2]) - tc2 * (CA * b[3])
                     - (P * b[4]) * td0 + (R * b[5]) * td1 + (P * b[6]) * td2
                     + (R * b[7]) * td3 - (P * b[8]) * td4;
      O3[5 * w + 3] += I5 * (b[7] * ta + b[0] * tb3)
                     + tc1 * (CB * b[3]) + tc2 * (CB * b[2])
                     + (Q * b[5]) * td0 + (Q * b[4]) * td1 + (R * b[7]) * td2
                     + (R * b[6] + Q * b[8]) * td3 + (Q * b[7]) * td4;
      O3[5 * w + 4] += I5 * (b[8] * ta + b[0] * tb4)
                     - tc0 * (CB * b[1]) + tc2 * (CB * b[3])
                     - (Q * b[5]) * td1 - (P * b[8]) * td2 + (Q * b[7]) * td3 - (P * b[6]) * td4;
    }
  }

  #pragma unroll
  for (int m = 1; m < 8; m <<= 1) {
    #pragma unroll
    for (int i = 0; i < 8; ++i) O0[i] += __shfl_xor(O0[i], m);
    #pragma unroll
    for (int i = 0; i < 9; ++i) O2[i] += __shfl_xor(O2[i], m);
    #pragma unroll
    for (int i = 0; i < 10; ++i) O3[i] += __shfl_xor(O3[i], m);
  }

  if (sl == 0) {
    const float S26 = 0.19611613513818404f, S14 = 0.2672612419124244f, S8 = 0.35355339059327373f;
    const float S13 = 0.2773500981126146f;
    float di = rsqrtf((float)cn);
    float F[27];
    #pragma unroll
    for (int w = 0; w < 8; ++w) F[w] = S26 * di * O0[w];
    #pragma unroll
    for (int i = 0; i < 9; ++i) F[8 + i] = S14 * di * O2[i];
    #pragma unroll
    for (int i = 0; i < 10; ++i) F[17 + i] = S8 * di * O3[i];

    float h[9];
    float t0 = 0;
    #pragma unroll
    for (int u = 0; u < 8; ++u) t0 += F[u] * w3[u];
    h[0] = S13 * t0;
    #pragma unroll
    for (int jj = 0; jj < 3; ++jj) {
      float s1 = 0;
      #pragma unroll
      for (int u = 0; u < 3; ++u) s1 += F[8 + 3 * u + jj] * w3[8 + u];
      h[1 + jj] = S13 * I3 * s1;
    }
    #pragma unroll
    for (int K = 0; K < 5; ++K)
      h[4 + K] = S13 * I5 * (F[17 + K] * w3[11] + F[22 + K] * w3[12]);

    float4* o4 = (float4*)(hh + (size_t)n * 16);
    o4[0] = make_float4(h[0], h[1], h[2], h[3]);
    o4[1] = make_float4(h[4], h[5], h[6], h[7]);
    o4[2] = make_float4(h[8], 0.f, 0.f, 0.f);
  }
}

// ---------- layer 3 gather + molecule reduce ----------
__global__ void k_gather3(const int* __restrict__ offs, const int* __restrict__ cnt,
                          const int* __restrict__ srcs, const float4* __restrict__ eb4,
                          const float* __restrict__ hh, const int* __restrict__ batch,
                          float* __restrict__ out) {
  int tid = blockIdx.x * 256 + threadIdx.x;
  int n = tid >> 3, sl = tid & 7;
  if (n >= NNODES) return;
  int beg = offs[n], cn = cnt[n];
  float v = 0.f;
  for (int j = sl; j < cn; j += 8) {
    int p = beg + j;
    int s = srcs[p];
    float4 ebv = eb4[p];
    float b[9]; make_b(ebv.w, ebv.x, ebv.y, ebv.z, b);
    const float4* Hf = (const float4*)(hh + (size_t)s * 16);
    float4 hA = Hf[0], hB = Hf[1];
    float h8 = Hf[2].x;
    v += b[0] * hA.x + b[1] * hA.y + b[2] * hA.z + b[3] * hA.w
       + b[4] * hB.x + b[5] * hB.y + b[6] * hB.z + b[7] * hB.w
       + b[8] * h8;
  }
  #pragma unroll
  for (int m = 1; m < 8; m <<= 1) v += __shfl_xor(v, m);
  if (sl == 0) {
    float di = rsqrtf((float)cn);
    unsafeAtomicAdd(out + batch[n], v * di * 0.2f);  // /sqrt(apm)=/5
  }
}

extern "C" void kernel_launch(void* const* d_in, const int* in_sizes, int n_in,
                              void* d_out, int out_size, void* d_ws, size_t ws_size,
                              hipStream_t stream) {
  const float* positions = (const float*)d_in[0];
  const float* x         = (const float*)d_in[1];
  const float* edge_attr = (const float*)d_in[2];
  const float* lin_w     = (const float*)d_in[3];
  const float* lin_b     = (const float*)d_in[4];
  const float* w_tp1     = (const float*)d_in[5];
  const float* w_tp2     = (const float*)d_in[6];
  const float* w_tp3     = (const float*)d_in[7];
  const int*   edge_src  = (const int*)d_in[8];
  const int*   edge_dst  = (const int*)d_in[9];
  const int*   batch     = (const int*)d_in[10];
  float* out = (float*)d_out;

  int*   cnt  = (int*)d_ws + OFF_CNT;
  int*   offs = (int*)d_ws + OFF_OFFS;
  int*   curs = (int*)d_ws + OFF_CURS;
  int*   bsum = (int*)d_ws + OFF_BSUM;
  int*   srcs = (int*)d_ws + OFF_SRCS;
  float4* eb4 = (float4*)((float*)d_ws + OFF_EB4);
  unsigned int* gb = (unsigned int*)((float*)d_ws + OFF_GB);
  unsigned int* tb = (unsigned int*)((float*)d_ws + OFF_TB);
  float* hh   = (float*)d_ws + OFF_HH;

  dim3 blk256(256);
  dim3 gEdge((NEDGES + 255) / 256);
  dim3 gNode256((NNODES + 255) / 256);
  dim3 gCoop((NNODES * 8 + 255) / 256);

  k_prep<<<gNode256, blk256, 0, stream>>>(x, lin_w, lin_b, w_tp1, gb, cnt, out, out_size);
  k_count<<<gEdge, blk256, 0, stream>>>(edge_dst, cnt);
  k_scanA<<<dim3(NBLK), blk256, 0, stream>>>(cnt, offs, bsum);
  k_scanB<<<dim3(1), blk256, 0, stream>>>(bsum);
  k_scanC<<<dim3(NBLK), blk256, 0, stream>>>(offs, curs, bsum);
  k_fill<<<gEdge, blk256, 0, stream>>>(positions, edge_attr, edge_src, edge_dst, curs, srcs, eb4);
  k_gather1t<<<gCoop, blk256, 0, stream>>>(offs, cnt, srcs, eb4, gb, w_tp2, tb);
  k_edge2c<<<gCoop, blk256, 0, stream>>>(offs, cnt, srcs, eb4, tb, w_tp3, hh);
  k_gather3<<<gCoop, blk256, 0, stream>>>(offs, cnt, srcs, eb4, hh, batch, out);
}